// Round 4
// baseline (291.856 us; speedup 1.0000x reference)
//
#include <hip/hip_runtime.h>
#include <hip/hip_bf16.h>
#include <cmath>

#define B_   2
#define S_   2048
#define D_   2048
#define H_   32
#define HKV_ 8
#define HD_  64
// G = H/HKV = 4

using bf16 = __hip_bfloat16;
typedef __bf16    bf16x8 __attribute__((ext_vector_type(8)));
typedef float     floatx4 __attribute__((ext_vector_type(4)));
typedef _Float16  half4 __attribute__((ext_vector_type(4)));
typedef _Float16  half8 __attribute__((ext_vector_type(8)));
typedef _Float16  half2v __attribute__((ext_vector_type(2)));

#if __has_builtin(__builtin_amdgcn_exp2f)
#define EXP2(x) __builtin_amdgcn_exp2f(x)
#else
#define EXP2(x) exp2f(x)
#endif

#define QSCALE 0.18033688011112042f   // 0.125 * log2(e)

__device__ inline void async16(const void* g, void* l) {
  __builtin_amdgcn_global_load_lds(
      (const __attribute__((address_space(1))) void*)g,
      (__attribute__((address_space(3))) void*)l, 16, 0, 0);
}

// cvt_pkrtz returns __fp16x2; bit-cast to our _Float16x2
__device__ inline half2v pkrtz(float a, float b) {
  return __builtin_bit_cast(half2v, __builtin_amdgcn_cvt_pkrtz(a, b));
}

#define MFMA32B(a, b, c) __builtin_amdgcn_mfma_f32_16x16x32_bf16((a), (b), (c), 0, 0, 0)
#define MFMA16H(a, b, c) __builtin_amdgcn_mfma_f32_16x16x16f16((a), (b), (c), 0, 0, 0)

// ---------- fused fp32->bf16 conversion for all 5 tensors (wq pre-scaled) ---
// wq/wk/wv destinations are slices of one concatenated Wcat[3072][2048].
__global__ void f2b_all(const float* __restrict__ x,  const float* __restrict__ wq,
                        const float* __restrict__ wk, const float* __restrict__ wv,
                        const float* __restrict__ wo,
                        bf16* __restrict__ xb,  bf16* __restrict__ wqb,
                        bf16* __restrict__ wkb, bf16* __restrict__ wvb,
                        bf16* __restrict__ wob) {
  const int i = blockIdx.x * blockDim.x + threadIdx.x;
  const float* src; bf16* dst; int off; float scale = 1.0f;
  if (i < 1048576)      { src = x;  dst = xb;  off = 0; }
  else if (i < 1572864) { src = wq; dst = wqb; off = 1048576; scale = QSCALE; }
  else if (i < 1703936) { src = wk; dst = wkb; off = 1572864; }
  else if (i < 1835008) { src = wv; dst = wvb; off = 1703936; }
  else                  { src = wo; dst = wob; off = 1835008; }
  const int j = i - off;
  float4 a  = ((const float4*)src)[2 * j];
  float4 b2 = ((const float4*)src)[2 * j + 1];
  alignas(16) bf16 t[8];
  t[0] = __float2bfloat16(a.x * scale);  t[1] = __float2bfloat16(a.y * scale);
  t[2] = __float2bfloat16(a.z * scale);  t[3] = __float2bfloat16(a.w * scale);
  t[4] = __float2bfloat16(b2.x * scale); t[5] = __float2bfloat16(b2.y * scale);
  t[6] = __float2bfloat16(b2.z * scale); t[7] = __float2bfloat16(b2.w * scale);
  ((uint4*)dst)[j] = *(const uint4*)t;
}

// -------------------- 128-tile GEMM body (gemm_o) ---------------------------
__device__ inline void gemm_body(const bf16* __restrict__ Ag, const bf16* __restrict__ Bg,
                                 const float* __restrict__ bias,
                                 float* __restrict__ C, int Ncol, int K, int bm, int colb,
                                 bf16* As, bf16* Bs) {
  const int tid  = threadIdx.x;
  const int wid  = tid >> 6, lane = tid & 63;
  const int lm   = lane & 15, quad = lane >> 4;
  const int wm   = (wid >> 1) * 64, wn = (wid & 1) * 64;

  floatx4 acc[4][4] = {};

  const int l0 = tid * 8;
  const int r0 = l0 >> 5, c0 = l0 & 31;
  const int r1 = r0 + 64;

  for (int k0 = 0; k0 < K; k0 += 32) {
    async16(Ag + (size_t)r0 * K + k0 + c0, &As[l0]);
    async16(Ag + (size_t)r1 * K + k0 + c0, &As[l0 + 2048]);
    async16(Bg + (size_t)r0 * K + k0 + c0, &Bs[l0]);
    async16(Bg + (size_t)r1 * K + k0 + c0, &Bs[l0 + 2048]);
    asm volatile("s_waitcnt vmcnt(0)" ::: "memory");
    __syncthreads();

    bf16x8 aF[4], bF[4];
#pragma unroll
    for (int mi = 0; mi < 4; ++mi)
      aF[mi] = *(const bf16x8*)&As[(wm + mi * 16 + lm) * 32 + quad * 8];
#pragma unroll
    for (int ni = 0; ni < 4; ++ni)
      bF[ni] = *(const bf16x8*)&Bs[(wn + ni * 16 + lm) * 32 + quad * 8];
#pragma unroll
    for (int mi = 0; mi < 4; ++mi)
#pragma unroll
      for (int ni = 0; ni < 4; ++ni)
        acc[mi][ni] = MFMA32B(bF[ni], aF[mi], acc[mi][ni]);  // swapped: D^T
    __syncthreads();
  }

#pragma unroll
  for (int mi = 0; mi < 4; ++mi) {
    const int row = bm * 128 + wm + mi * 16 + lm;
#pragma unroll
    for (int ni = 0; ni < 4; ++ni) {
      const int col0 = colb + wn + ni * 16 + quad * 4;
      float4 bv4 = *(const float4*)&bias[col0];
      float4 o4;
      o4.x = acc[mi][ni][0] + bv4.x; o4.y = acc[mi][ni][1] + bv4.y;
      o4.z = acc[mi][ni][2] + bv4.z; o4.w = acc[mi][ni][3] + bv4.w;
      *(float4*)&C[(size_t)row * Ncol + col0] = o4;
    }
  }
}

// Plain GEMM (O-projection): C fp32 = A * B^T + bias
__global__ __launch_bounds__(256, 2)
void gemm_o(const bf16* __restrict__ A, const bf16* __restrict__ Bm,
            const float* __restrict__ bias, float* __restrict__ C,
            int Ncol, int K) {
  __shared__ bf16 As[128 * 32];
  __shared__ bf16 Bs[128 * 32];
  const int bn = blockIdx.x, bm = blockIdx.y;
  gemm_body(A + (size_t)bm * 128 * K, Bm + (size_t)bn * 128 * K, bias,
            C, Ncol, K, bm, bn * 128, As, Bs);
}

// ===================== 8-phase 128x384 fused QKV GEMM =======================
// 256 blocks (32 bm x 8 bn) = exactly 1/CU. 512 thr (8 waves 2Mx4N, wave 64x96).
// BK=64, double-buffered; per K-tile 8 staging instrs/wave (A half = 1, B half
// = 3), 4 phases x 12 MFMA, counted vmcnt(8) twice/tile (never 0 steady-state).
// XOR swizzle (row bit3 <-> col bit4) on global source AND ds_read address;
// LDS dest linear. B = concatenated [wq(2048) | wk(512) | wv(512)] rows; each
// 16-col output fragment dispatches to Q / K / V-tiled epilogue.
__global__ __launch_bounds__(512, 2)
void gemm_qkv8(const bf16* __restrict__ xb, const bf16* __restrict__ Wcat,
               const float* __restrict__ bq, const float* __restrict__ bk,
               const float* __restrict__ bv,
               bf16* __restrict__ Qo, bf16* __restrict__ Ko,
               _Float16* __restrict__ VG) {
  constexpr int NT = D_ / 64;   // 32 K-tiles
  __shared__ bf16 L[65536];     // 128 KiB: [buf2][ A:2x(128x32) | B:2x(384x32) ]

  const int id = blockIdx.x;
  const int bn = id & 7;        // XCD-pinned weight slab (round-robin dispatch)
  const int bm = id >> 3;

  const int tid = threadIdx.x;
  const int wid = tid >> 6, lane = tid & 63;
  const int lm = lane & 15, quad = lane >> 4;
  const int wm = wid >> 2, wn = wid & 3;   // 2M x 4N

  // ds_read bases (element units), XOR-swizzled col offset
  const int cOff = (quad * 8) ^ (((lm >> 3) & 1) << 4);
  const bf16* LA0 = L + (wm * 64 + lm) * 32 + cOff;          // +BUF +h*4096 +mi*512
  const bf16* LB0 = L + 8192 + (wn * 96 + lm) * 32 + cOff;   // +BUF +h*12288 +ni*512

  // staging: thread covers row tid>>2 (+128*i for B instr i), 8 cols at
  // (tid&3)*8, source col pre-swizzled by row bit3 (= bit5 of tid).
  const int r0 = tid >> 2;
  const int csrc = ((tid & 3) * 8) ^ (((tid >> 5) & 1) << 4);
  const bf16* Asrc = xb   + (size_t)(bm * 128 + r0) * D_ + csrc;
  const bf16* Bs0  = Wcat + (size_t)(bn * 384 + r0) * D_ + csrc;
  const bf16* Bs1  = Bs0 + (size_t)128 * D_;
  const bf16* Bs2  = Bs0 + (size_t)256 * D_;
  bf16* Ld = L + tid * 8;   // linear dest (wave base + lane*16B)

  floatx4 acc[4][6] = {};

#define BARX() { asm volatile("" ::: "memory"); __builtin_amdgcn_s_barrier(); \
                 asm volatile("" ::: "memory"); }
#define LGKM0() asm volatile("s_waitcnt lgkmcnt(0)" ::: "memory")
#define STG_A(tt, hh, DB)  async16(Asrc + (tt) * 64 + (hh) * 32, (DB) + (hh) * 4096)
#define STG_B0(tt, hh, DB) async16(Bs0  + (tt) * 64 + (hh) * 32, (DB) + 8192 + (hh) * 12288)
#define STG_B1(tt, hh, DB) async16(Bs1  + (tt) * 64 + (hh) * 32, (DB) + 8192 + (hh) * 12288 + 4096)
#define STG_B2(tt, hh, DB) async16(Bs2  + (tt) * 64 + (hh) * 32, (DB) + 8192 + (hh) * 12288 + 8192)

  // prologue: G0(0) + G1(0) + G0(1) = 12 instrs; wait until G0(0) (4) landed.
  STG_A(0, 0, Ld); STG_B0(0, 0, Ld); STG_B1(0, 0, Ld); STG_B2(0, 0, Ld);
  STG_A(0, 1, Ld); STG_B0(0, 1, Ld); STG_B1(0, 1, Ld); STG_B2(0, 1, Ld);
  STG_A(1, 0, Ld + 32768); STG_B0(1, 0, Ld + 32768);
  STG_B1(1, 0, Ld + 32768); STG_B2(1, 0, Ld + 32768);
  asm volatile("s_waitcnt vmcnt(8)" ::: "memory");
  BARX();

  auto tile = [&](int t, const int BUF) __attribute__((always_inline)) {
    const bf16* LA = LA0 + BUF;
    const bf16* LB = LB0 + BUF;
    bf16* SD  = Ld + BUF;             // tile t+2: same buf, k0 slots (dead)
    bf16* SDo = Ld + (BUF ^ 32768);   // tile t+1: other buf, k1 slots
    const bool s1 = (t + 1) < NT, s2 = (t + 2) < NT;
    bf16x8 aF[4], bF[3];

    // ---- phase 1: k-half 0, ni 0-2
#pragma unroll
    for (int i = 0; i < 4; ++i) aF[i] = *(const bf16x8*)(LA + i * 512);
#pragma unroll
    for (int i = 0; i < 3; ++i) bF[i] = *(const bf16x8*)(LB + i * 512);
    if (s1) { STG_A(t + 1, 1, SDo); STG_B0(t + 1, 1, SDo); }
    BARX(); LGKM0();
    __builtin_amdgcn_s_setprio(1);
#pragma unroll
    for (int mi = 0; mi < 4; ++mi)
#pragma unroll
      for (int ni = 0; ni < 3; ++ni)
        acc[mi][ni] = MFMA32B(bF[ni], aF[mi], acc[mi][ni]);
    __builtin_amdgcn_s_setprio(0);
    BARX();

    // ---- phase 2: k-half 0, ni 3-5 (aF held)
#pragma unroll
    for (int i = 0; i < 3; ++i) bF[i] = *(const bf16x8*)(LB + (i + 3) * 512);
    if (s1) { STG_B1(t + 1, 1, SDo); STG_B2(t + 1, 1, SDo); }
    BARX(); LGKM0();
    __builtin_amdgcn_s_setprio(1);
#pragma unroll
    for (int mi = 0; mi < 4; ++mi)
#pragma unroll
      for (int ni = 0; ni < 3; ++ni)
        acc[mi][ni + 3] = MFMA32B(bF[ni], aF[mi], acc[mi][ni + 3]);
    __builtin_amdgcn_s_setprio(0);
    // counted: ensure this tile's k1 granules (G1(t)) landed for phase 3
    if (s1) { asm volatile("s_waitcnt vmcnt(8)" ::: "memory"); }
    else    { asm volatile("s_waitcnt vmcnt(0)" ::: "memory"); }
    BARX();

    // ---- phase 3: k-half 1, ni 0-2
#pragma unroll
    for (int i = 0; i < 4; ++i) aF[i] = *(const bf16x8*)(LA + 4096 + i * 512);
#pragma unroll
    for (int i = 0; i < 3; ++i) bF[i] = *(const bf16x8*)(LB + 12288 + i * 512);
    if (s2) { STG_A(t + 2, 0, SD); STG_B0(t + 2, 0, SD); }
    BARX(); LGKM0();
    __builtin_amdgcn_s_setprio(1);
#pragma unroll
    for (int mi = 0; mi < 4; ++mi)
#pragma unroll
      for (int ni = 0; ni < 3; ++ni)
        acc[mi][ni] = MFMA32B(bF[ni], aF[mi], acc[mi][ni]);
    __builtin_amdgcn_s_setprio(0);
    BARX();

    // ---- phase 4: k-half 1, ni 3-5
#pragma unroll
    for (int i = 0; i < 3; ++i) bF[i] = *(const bf16x8*)(LB + 12288 + (i + 3) * 512);
    if (s2) { STG_B1(t + 2, 0, SD); STG_B2(t + 2, 0, SD); }
    BARX(); LGKM0();
    __builtin_amdgcn_s_setprio(1);
#pragma unroll
    for (int mi = 0; mi < 4; ++mi)
#pragma unroll
      for (int ni = 0; ni < 3; ++ni)
        acc[mi][ni + 3] = MFMA32B(bF[ni], aF[mi], acc[mi][ni + 3]);
    __builtin_amdgcn_s_setprio(0);
    // counted: ensure next tile's k0 granules (G0(t+1)) landed
    if (s2)      { asm volatile("s_waitcnt vmcnt(8)" ::: "memory"); }
    else if (s1) { asm volatile("s_waitcnt vmcnt(4)" ::: "memory"); }
    else         { asm volatile("s_waitcnt vmcnt(0)" ::: "memory"); }
    BARX();
  };

  for (int t = 0; t < NT; t += 2) { tile(t, 0); tile(t + 1, 32768); }

#undef BARX
#undef LGKM0
#undef STG_A
#undef STG_B0
#undef STG_B1
#undef STG_B2

  // -------- mixed epilogue: per 16-col fragment -> Q | K | V-tiled ----------
  // swapped layout: lane holds row = ..+lm, cols col0..col0+3 (col0 = colf+quad*4)
#pragma unroll
  for (int mi = 0; mi < 4; ++mi) {
    const int row = bm * 128 + wm * 64 + mi * 16 + lm;
#pragma unroll
    for (int ni = 0; ni < 6; ++ni) {
      const int colf = bn * 384 + wn * 96 + ni * 16;   // wave-uniform, 16-aligned
      const int col0 = colf + quad * 4;
      if (colf < 2048) {                       // ---- Q (pre-scaled, bf16)
        float4 bv4 = *(const float4*)&bq[col0];
        alignas(8) bf16 t4[4];
#pragma unroll
        for (int r = 0; r < 4; ++r)
          t4[r] = __float2bfloat16(acc[mi][ni][r] + ((const float*)&bv4)[r] * QSCALE);
        *(uint2*)&Qo[(size_t)row * (H_ * HD_) + col0] = *(const uint2*)t4;
      } else if (colf < 2560) {                // ---- K (bf16 row-major)
        const int ck = col0 - 2048;
        float4 bv4 = *(const float4*)&bk[ck];
        alignas(8) bf16 t4[4];
#pragma unroll
        for (int r = 0; r < 4; ++r)
          t4[r] = __float2bfloat16(acc[mi][ni][r] + ((const float*)&bv4)[r]);
        *(uint2*)&Ko[(size_t)row * (HKV_ * HD_) + ck] = *(const uint2*)t4;
      } else {                                 // ---- V (tiled f16, nh-paired)
        // layout per (b,kvh,tile) 4096-f16 block:
        //   off = ((kc*2 + nh/2)*4 + qd)*128 + lmw*8 + (nh&1)*4 + j
        // -> attn lane (quad,lm) reads b128 at row kc*8+nh2*4+quad, byte lm*16
        const int cv = col0 - 2560;            // kv-head*64 + hd
        const int kvh = cv >> 6, hd = cv & 63;
        const int nh = hd >> 4;                // lmw = quad*4 + r
        const int bb = row >> 11, s2 = row & 2047;
        const int tl = s2 >> 6, kvin = s2 & 63;
        const int kc = kvin >> 4, qd = (kvin >> 2) & 3, j = kvin & 3;
        const size_t base = ((size_t)((bb * 8 + kvh) * 32 + tl) << 12) +
                            (size_t)(((kc * 2 + (nh >> 1)) * 4 + qd) * 128 +
                                     (nh & 1) * 4 + j);
        float4 bv4 = *(const float4*)&bv[cv];
#pragma unroll
        for (int r = 0; r < 4; ++r)
          VG[base + (size_t)(quad * 4 + r) * 8] =
              (_Float16)(acc[mi][ni][r] + ((const float*)&bv4)[r]);
      }
    }
  }
}

// -------------------- causal GQA flash attention, v6 ------------------------
// Block = (pair, b, kvh): 4 waves = 4 heads of one GQA group sharing K/V LDS.
// Each wave owns two 16-row q-tiles (hi=127-pair, lo=pair), interleaved kv-loop.
// v6: single merged kc-loop (QK -> mask-in-f32 -> pkrtz -> PV) for ILP;
// V reads as 2x ds_read_b128 per kc (nh-paired layout); setprio around MFMA
// clusters; launch_bounds(256,5) -> 5 blocks/CU (LDS 32KiB x 5 = 160KiB).
__global__ __launch_bounds__(256, 5)
void attn_kernel(const bf16* __restrict__ Q, const bf16* __restrict__ K,
                 const _Float16* __restrict__ VG, bf16* __restrict__ O) {
  const int tid = threadIdx.x;
  const int wid = tid >> 6, lane = tid & 63;
  const int lm = lane & 15, quad = lane >> 4;

  // XCD-aware swizzle: group (b,kvh) pinned to one XCD (2 groups/XCD)
  const int n   = blockIdx.y * 64 + blockIdx.x;   // grid (64, 16)
  const int x3  = n & 7, b1 = (n >> 3) & 1;
  const int pair = n >> 4;                        // 0..63
  const int grp  = x3 * 2 + b1;                   // 0..15 == b*8 + kvh
  const int b    = grp >> 3, kvh = grp & 7;
  const int head = kvh * 4 + wid;

  const int hi = 127 - pair, lo = pair;
  const int nt_hi = (hi >> 2) + 1;                // 17..32
  const int nt_lo = (lo >> 2) + 1;

  __shared__ bf16     Ks[2 * 64 * 64];   // [buf][hd-half][kv][32]
  __shared__ _Float16 Vs[2 * 64 * 64];   // [buf][tiled 4096, nh-paired]

  const int tb[2] = {hi * 16, lo * 16};

  bf16x8 qf[2][2];
#pragma unroll
  for (int tt = 0; tt < 2; ++tt) {
    const size_t qg = ((size_t)(b * S_ + tb[tt] + lm)) * (H_ * HD_) + head * HD_;
#pragma unroll
    for (int kf = 0; kf < 2; ++kf)
      qf[tt][kf] = *(const bf16x8*)&Q[qg + kf * 32 + quad * 8];
  }

  half4 onesh;
#pragma unroll
  for (int j = 0; j < 4; ++j) onesh[j] = (_Float16)1.0f;

  floatx4 o_acc[2][4] = {};
  floatx4 lacc[2] = {};

  auto stage = [&](int t, int buf) {
    const int tr = tid >> 2;
    const int tc = (tid & 3) * 8;
#pragma unroll
    for (int c = 0; c < 2; ++c) {
      async16(&K[(size_t)(b * S_ + t * 64 + tr) * (HKV_ * HD_) + kvh * HD_ + c * 32 + tc],
              &Ks[buf * 4096 + c * 2048 + tid * 8]);
      async16(&VG[((size_t)(grp * 32 + t) << 12) + c * 2048 + tid * 8],
              &Vs[buf * 4096 + c * 2048 + tid * 8]);
    }
  };

  stage(0, 0);

  for (int t = 0; t < nt_hi; ++t) {
    const int cur = t & 1;
    asm volatile("s_waitcnt vmcnt(0)" ::: "memory");
    __syncthreads();
    if (t + 1 < nt_hi) stage(t + 1, cur ^ 1);

    const bf16*     Kb = &Ks[cur * 4096];
    const _Float16* Vb = &Vs[cur * 4096];
    const int t0 = t * 64;
    const int nact = (t < nt_lo) ? 2 : 1;

    int kcmax[2], kcross[2];
#pragma unroll
    for (int tt = 0; tt < 2; ++tt) {
      const int rel = tb[tt] + 15 - t0;
      kcmax[tt]  = (tt < nact) ? ((rel >> 4) >= 3 ? 4 : (rel >> 4) + 1) : 0;
      kcross[tt] = rel >> 4;
    }

    half4 ps[2] = {};   // per-tile row-sum presum (f16)

    // -------- merged kc loop: QK -> softmax -> PV, pipelineable ------------
#pragma unroll
    for (int kc = 0; kc < 4; ++kc) {
      if (kc >= kcmax[0]) break;   // kcmax[0] >= kcmax[1] always
      bf16x8 kb0 = *(const bf16x8*)&Kb[(kc * 16 + lm) * 32 + quad * 8];
      bf16x8 kb1 = *(const bf16x8*)&Kb[2048 + (kc * 16 + lm) * 32 + quad * 8];

      floatx4 sT[2];
      __builtin_amdgcn_s_setprio(1);
#pragma unroll
      for (int tt = 0; tt < 2; ++tt) {
        if (kc >= kcmax[tt]) continue;
        floatx4 s0 = {};
        s0 = MFMA32B(kb0, qf[tt][0], s0);
        sT[tt] = MFMA32B(kb1, qf[tt][1], s0);
      }
      __builtin_amdgcn_s_setprio(0);

      // V fragments for this kc: 2 x b128 (nh pairs 0/1 and 2/3)
      half8 v0 = *(const half8*)&Vb[(kc * 8 + quad) * 128 + lm * 8];
      half8 v1 = *(const half8*)&Vb[(kc * 8 + 4 + quad) * 128 + lm * 8];
      half4 v0l = __builtin_shufflevector(v0, v0, 0, 1, 2, 3);
      half4 v0h = __builtin_shufflevector(v0, v0, 4, 5, 6, 7);
      half4 v1l = __builtin_shufflevector(v1, v1, 0, 1, 2, 3);
      half4 v1h = __builtin_shufflevector(v1, v1, 4, 5, 6, 7);

      half4 pbk[2];
#pragma unroll
      for (int tt = 0; tt < 2; ++tt) {
        if (kc >= kcmax[tt]) continue;
        floatx4 s = sT[tt];
        if (kc == kcross[tt]) {
          const int qrel = tb[tt] + lm - t0;   // q - t0
#pragma unroll
          for (int r = 0; r < 4; ++r)
            if (kc * 16 + quad * 4 + r > qrel) s[r] = -__builtin_inff();
        }
        half2v c0 = pkrtz(EXP2(s[0]), EXP2(s[1]));
        half2v c1 = pkrtz(EXP2(s[2]), EXP2(s[3]));
        half4 pk = __builtin_shufflevector(c0, c1, 0, 1, 2, 3);
        pbk[tt] = pk;
        ps[tt] += pk;
      }

      __builtin_amdgcn_s_setprio(1);
#pragma unroll
      for (int tt = 0; tt < 2; ++tt) {
        if (kc >= kcmax[tt]) continue;
        o_acc[tt][0] = MFMA16H(v0l, pbk[tt], o_acc[tt][0]);
        o_acc[tt][1] = MFMA16H(v0h, pbk[tt], o_acc[tt][1]);
        o_acc[tt][2] = MFMA16H(v1l, pbk[tt], o_acc[tt][2]);
        o_acc[tt][3] = MFMA16H(v1h, pbk[tt], o_acc[tt][3]);
      }
      __builtin_amdgcn_s_setprio(0);
    }

    // row sums: one ones-MFMA per q-tile
#pragma unroll
    for (int tt = 0; tt < 2; ++tt)
      if (kcmax[tt]) lacc[tt] = MFMA16H(onesh, ps[tt], lacc[tt]);
  }

#pragma unroll
  for (int tt = 0; tt < 2; ++tt) {
    const float rl = 1.f / lacc[tt][0];
    const size_t rowg = (size_t)(b * S_ + tb[tt] + lm);
#pragma unroll
    for (int nh = 0; nh < 4; ++nh) {
      alignas(8) bf16 tmp[4];
#pragma unroll
      for (int r = 0; r < 4; ++r)
        tmp[r] = __float2bfloat16(o_acc[tt][nh][r] * rl);
      *(uint2*)&O[rowg * (H_ * HD_) + head * HD_ + nh * 16 + quad * 4] = *(uint2*)tmp;
    }
  }
}

// ---------------------------------------------------------------------------
extern "C" void kernel_launch(void* const* d_in, const int* in_sizes, int n_in,
                              void* d_out, int out_size, void* d_ws, size_t ws_size,
                              hipStream_t stream) {
  (void)in_sizes; (void)n_in; (void)out_size; (void)ws_size;
  const float* x  = (const float*)d_in[0];
  const float* wq = (const float*)d_in[1];
  const float* bq = (const float*)d_in[2];
  const float* wk = (const float*)d_in[3];
  const float* bk = (const float*)d_in[4];
  const float* wv = (const float*)d_in[5];
  const float* bv = (const float*)d_in[6];
  const float* wo = (const float*)d_in[7];
  const float* bo = (const float*)d_in[8];
  float* out = (float*)d_out;

  const int M = B_ * S_;        // 4096
  const int E = H_ * HD_;       // 2048
  const int EKV = HKV_ * HD_;   // 512

  char* ws = (char*)d_ws;
  size_t off = 0;
  auto alloc = [&](size_t bytes) {
    char* p = ws + off;
    off += (bytes + 255) & ~(size_t)255;
    return p;
  };
  bf16* xb   = (bf16*)alloc((size_t)M * D_ * 2);
  bf16* Wcat = (bf16*)alloc((size_t)(E + 2 * EKV) * D_ * 2);   // [wq|wk|wv] rows
  bf16* wob  = (bf16*)alloc((size_t)D_ * E * 2);
  bf16* Qb   = (bf16*)alloc((size_t)M * E * 2);
  bf16* Kb   = (bf16*)alloc((size_t)M * EKV * 2);
  _Float16* VG = (_Float16*)alloc((size_t)M * EKV * 2);  // tiled V, f16
  bf16* Ob   = (bf16*)alloc((size_t)M * E * 2);

  bf16* wqb = Wcat;                          // rows 0..2047 (pre-scaled)
  bf16* wkb = Wcat + (size_t)E * D_;         // rows 2048..2559
  bf16* wvb = Wcat + (size_t)(E + EKV) * D_; // rows 2560..3071

  f2b_all<<<9216, 256, 0, stream>>>(x, wq, wk, wv, wo, xb, wqb, wkb, wvb, wob);

  gemm_qkv8<<<dim3(256), dim3(512), 0, stream>>>(xb, Wcat, bq, bk, bv,
                                                 Qb, Kb, VG);

  attn_kernel<<<dim3(64, 16), 256, 0, stream>>>(Qb, Kb, VG, Ob);

  gemm_o<<<dim3(D_ / 128, M / 128), 256, 0, stream>>>(Ob, wob, bo, out, D_, D_);
}

// Round 6
// 284.212 us; speedup vs baseline: 1.0269x; 1.0269x over previous
//
#include <hip/hip_runtime.h>
#include <hip/hip_bf16.h>
#include <cmath>

#define B_   2
#define S_   2048
#define D_   2048
#define H_   32
#define HKV_ 8
#define HD_  64
// G = H/HKV = 4

using bf16 = __hip_bfloat16;
typedef __bf16    bf16x8 __attribute__((ext_vector_type(8)));
typedef float     floatx4 __attribute__((ext_vector_type(4)));
typedef _Float16  half4 __attribute__((ext_vector_type(4)));
typedef _Float16  half8 __attribute__((ext_vector_type(8)));
typedef _Float16  half2v __attribute__((ext_vector_type(2)));

#if __has_builtin(__builtin_amdgcn_exp2f)
#define EXP2(x) __builtin_amdgcn_exp2f(x)
#else
#define EXP2(x) exp2f(x)
#endif

#define QSCALE 0.18033688011112042f   // 0.125 * log2(e)

__device__ inline void async16(const void* g, void* l) {
  __builtin_amdgcn_global_load_lds(
      (const __attribute__((address_space(1))) void*)g,
      (__attribute__((address_space(3))) void*)l, 16, 0, 0);
}

// cvt_pkrtz returns __fp16x2; bit-cast to our _Float16x2
__device__ inline half2v pkrtz(float a, float b) {
  return __builtin_bit_cast(half2v, __builtin_amdgcn_cvt_pkrtz(a, b));
}

#define MFMA32B(a, b, c) __builtin_amdgcn_mfma_f32_16x16x32_bf16((a), (b), (c), 0, 0, 0)
#define MFMA16H(a, b, c) __builtin_amdgcn_mfma_f32_16x16x16f16((a), (b), (c), 0, 0, 0)

#define BARX() { asm volatile("" ::: "memory"); __builtin_amdgcn_s_barrier(); \
                 asm volatile("" ::: "memory"); }
#define LGKM0() asm volatile("s_waitcnt lgkmcnt(0)" ::: "memory")

// ---------- fused fp32->bf16 conversion for all 5 tensors (wq pre-scaled) ---
// wq/wk/wv destinations are slices of one concatenated Wcat[3072][2048].
__global__ void f2b_all(const float* __restrict__ x,  const float* __restrict__ wq,
                        const float* __restrict__ wk, const float* __restrict__ wv,
                        const float* __restrict__ wo,
                        bf16* __restrict__ xb,  bf16* __restrict__ wqb,
                        bf16* __restrict__ wkb, bf16* __restrict__ wvb,
                        bf16* __restrict__ wob) {
  const int i = blockIdx.x * blockDim.x + threadIdx.x;
  const float* src; bf16* dst; int off; float scale = 1.0f;
  if (i < 1048576)      { src = x;  dst = xb;  off = 0; }
  else if (i < 1572864) { src = wq; dst = wqb; off = 1048576; scale = QSCALE; }
  else if (i < 1703936) { src = wk; dst = wkb; off = 1572864; }
  else if (i < 1835008) { src = wv; dst = wvb; off = 1703936; }
  else                  { src = wo; dst = wob; off = 1835008; }
  const int j = i - off;
  float4 a  = ((const float4*)src)[2 * j];
  float4 b2 = ((const float4*)src)[2 * j + 1];
  alignas(16) bf16 t[8];
  t[0] = __float2bfloat16(a.x * scale);  t[1] = __float2bfloat16(a.y * scale);
  t[2] = __float2bfloat16(a.z * scale);  t[3] = __float2bfloat16(a.w * scale);
  t[4] = __float2bfloat16(b2.x * scale); t[5] = __float2bfloat16(b2.y * scale);
  t[6] = __float2bfloat16(b2.z * scale); t[7] = __float2bfloat16(b2.w * scale);
  ((uint4*)dst)[j] = *(const uint4*)t;
}

// ===================== 2-phase/K-tile 128x384 fused QKV GEMM ================
// 256 blocks (32 bm x 8 bn) = 1/CU. 512 thr (8 waves 2Mx4N, wave 64x96).
// BK=64, double-buffered; 8 staging instrs/tile (4/phase), 2 phases x 24 MFMA,
// counted vmcnt(8) per phase (never 0 steady-state). XOR swizzle (row bit3 <->
// col bit4) on global source AND ds_read address; LDS dest linear.
// B = concatenated [wq(2048)|wk(512)|wv(512)] rows; 16-col output fragments
// dispatch to Q / K / V-tiled epilogues.
__global__ __launch_bounds__(512, 2)
void gemm_qkv8(const bf16* __restrict__ xb, const bf16* __restrict__ Wcat,
               const float* __restrict__ bq, const float* __restrict__ bk,
               const float* __restrict__ bv,
               bf16* __restrict__ Qo, bf16* __restrict__ Ko,
               _Float16* __restrict__ VG) {
  constexpr int NT = D_ / 64;   // 32 K-tiles
  __shared__ bf16 L[65536];     // 128 KiB: [buf2][ A:2x(128x32) | B:2x(384x32) ]

  const int id = blockIdx.x;
  const int bn = id & 7;        // XCD-pinned weight slab (round-robin dispatch)
  const int bm = id >> 3;

  const int tid = threadIdx.x;
  const int wid = tid >> 6, lane = tid & 63;
  const int lm = lane & 15, quad = lane >> 4;
  const int wm = wid >> 2, wn = wid & 3;   // 2M x 4N

  // ds_read bases (element units), XOR-swizzled col offset
  const int cOff = (quad * 8) ^ (((lm >> 3) & 1) << 4);
  const bf16* LA0 = L + (wm * 64 + lm) * 32 + cOff;          // +BUF +h*4096 +mi*512
  const bf16* LB0 = L + 8192 + (wn * 96 + lm) * 32 + cOff;   // +BUF +h*12288 +ni*512

  // staging: thread covers row tid>>2 (+128*i for B instr i), 8 cols at
  // (tid&3)*8, source col pre-swizzled by row bit3 (= bit5 of tid).
  const int r0 = tid >> 2;
  const int csrc = ((tid & 3) * 8) ^ (((tid >> 5) & 1) << 4);
  const bf16* Asrc = xb   + (size_t)(bm * 128 + r0) * D_ + csrc;
  const bf16* Bs0  = Wcat + (size_t)(bn * 384 + r0) * D_ + csrc;
  const bf16* Bs1  = Bs0 + (size_t)128 * D_;
  const bf16* Bs2  = Bs0 + (size_t)256 * D_;
  bf16* Ld = L + tid * 8;   // linear dest (wave base + lane*16B)

  floatx4 acc[4][6] = {};

#define STG_A(tt, hh, DB)  async16(Asrc + (tt) * 64 + (hh) * 32, (DB) + (hh) * 4096)
#define STG_B0(tt, hh, DB) async16(Bs0  + (tt) * 64 + (hh) * 32, (DB) + 8192 + (hh) * 12288)
#define STG_B1(tt, hh, DB) async16(Bs1  + (tt) * 64 + (hh) * 32, (DB) + 8192 + (hh) * 12288 + 4096)
#define STG_B2(tt, hh, DB) async16(Bs2  + (tt) * 64 + (hh) * 32, (DB) + 8192 + (hh) * 12288 + 8192)

  // prologue: t0 k0+k1 (8) + t1 k0 (4) = 12 instrs; wait until t0 k0 landed.
  STG_A(0, 0, Ld); STG_B0(0, 0, Ld); STG_B1(0, 0, Ld); STG_B2(0, 0, Ld);
  STG_A(0, 1, Ld); STG_B0(0, 1, Ld); STG_B1(0, 1, Ld); STG_B2(0, 1, Ld);
  STG_A(1, 0, Ld + 32768); STG_B0(1, 0, Ld + 32768);
  STG_B1(1, 0, Ld + 32768); STG_B2(1, 0, Ld + 32768);
  asm volatile("s_waitcnt vmcnt(8)" ::: "memory");
  BARX();

  auto tile = [&](int t, const int BUF) __attribute__((always_inline)) {
    const bf16* LA = LA0 + BUF;
    const bf16* LB = LB0 + BUF;
    bf16* SD  = Ld + BUF;             // tile t+2: same buf, k0 slots (dead)
    bf16* SDo = Ld + (BUF ^ 32768);   // tile t+1: other buf, k1 slots
    const bool s1 = (t + 1) < NT, s2 = (t + 2) < NT;
    bf16x8 aF[4], bF[6];

    // ---- phase A: k-half 0, all 24 MFMA
#pragma unroll
    for (int i = 0; i < 4; ++i) aF[i] = *(const bf16x8*)(LA + i * 512);
#pragma unroll
    for (int i = 0; i < 6; ++i) bF[i] = *(const bf16x8*)(LB + i * 512);
    if (s1) { STG_A(t + 1, 1, SDo); STG_B0(t + 1, 1, SDo);
              STG_B1(t + 1, 1, SDo); STG_B2(t + 1, 1, SDo); }
    BARX(); LGKM0();
    __builtin_amdgcn_s_setprio(1);
#pragma unroll
    for (int mi = 0; mi < 4; ++mi)
#pragma unroll
      for (int ni = 0; ni < 6; ++ni)
        acc[mi][ni] = MFMA32B(bF[ni], aF[mi], acc[mi][ni]);
    __builtin_amdgcn_s_setprio(0);
    // counted: this tile's k1 granules (staged in phase A of tile t-1) landed
    if (s1) { asm volatile("s_waitcnt vmcnt(8)" ::: "memory"); }
    else    { asm volatile("s_waitcnt vmcnt(0)" ::: "memory"); }
    BARX();

    // ---- phase B: k-half 1, all 24 MFMA
#pragma unroll
    for (int i = 0; i < 4; ++i) aF[i] = *(const bf16x8*)(LA + 4096 + i * 512);
#pragma unroll
    for (int i = 0; i < 6; ++i) bF[i] = *(const bf16x8*)(LB + 12288 + i * 512);
    if (s2) { STG_A(t + 2, 0, SD); STG_B0(t + 2, 0, SD);
              STG_B1(t + 2, 0, SD); STG_B2(t + 2, 0, SD); }
    BARX(); LGKM0();
    __builtin_amdgcn_s_setprio(1);
#pragma unroll
    for (int mi = 0; mi < 4; ++mi)
#pragma unroll
      for (int ni = 0; ni < 6; ++ni)
        acc[mi][ni] = MFMA32B(bF[ni], aF[mi], acc[mi][ni]);
    __builtin_amdgcn_s_setprio(0);
    // counted: next tile's k0 granules landed
    if (s2)      { asm volatile("s_waitcnt vmcnt(8)" ::: "memory"); }
    else if (s1) { asm volatile("s_waitcnt vmcnt(4)" ::: "memory"); }
    else         { asm volatile("s_waitcnt vmcnt(0)" ::: "memory"); }
    BARX();
  };

  for (int t = 0; t < NT; t += 2) { tile(t, 0); tile(t + 1, 32768); }

#undef STG_A
#undef STG_B0
#undef STG_B1
#undef STG_B2

  // -------- mixed epilogue: per 16-col fragment -> Q | K | V-tiled ----------
  // swapped layout: lane holds row = ..+lm, cols col0..col0+3 (col0 = colf+quad*4)
#pragma unroll
  for (int mi = 0; mi < 4; ++mi) {
    const int row = bm * 128 + wm * 64 + mi * 16 + lm;
#pragma unroll
    for (int ni = 0; ni < 6; ++ni) {
      const int colf = bn * 384 + wn * 96 + ni * 16;   // wave-uniform, 16-aligned
      const int col0 = colf + quad * 4;
      if (colf < 2048) {                       // ---- Q (pre-scaled, bf16)
        float4 bv4 = *(const float4*)&bq[col0];
        alignas(8) bf16 t4[4];
#pragma unroll
        for (int r = 0; r < 4; ++r)
          t4[r] = __float2bfloat16(acc[mi][ni][r] + ((const float*)&bv4)[r] * QSCALE);
        *(uint2*)&Qo[(size_t)row * (H_ * HD_) + col0] = *(const uint2*)t4;
      } else if (colf < 2560) {                // ---- K (bf16 row-major)
        const int ck = col0 - 2048;
        float4 bv4 = *(const float4*)&bk[ck];
        alignas(8) bf16 t4[4];
#pragma unroll
        for (int r = 0; r < 4; ++r)
          t4[r] = __float2bfloat16(acc[mi][ni][r] + ((const float*)&bv4)[r]);
        *(uint2*)&Ko[(size_t)row * (HKV_ * HD_) + ck] = *(const uint2*)t4;
      } else {                                 // ---- V (tiled f16, nh-paired)
        // layout per (b,kvh,tile) 4096-f16 block:
        //   off = ((kc*2 + nh/2)*4 + qd)*128 + lmw*8 + (nh&1)*4 + j
        // -> attn lane (quad,lm) reads b128 at row kc*8+nh2*4+quad, byte lm*16
        const int cv = col0 - 2560;            // kv-head*64 + hd
        const int kvh = cv >> 6, hd = cv & 63;
        const int nh = hd >> 4;                // lmw = quad*4 + r
        const int bb = row >> 11, s2 = row & 2047;
        const int tl = s2 >> 6, kvin = s2 & 63;
        const int kc = kvin >> 4, qd = (kvin >> 2) & 3, j = kvin & 3;
        const size_t base = ((size_t)((bb * 8 + kvh) * 32 + tl) << 12) +
                            (size_t)(((kc * 2 + (nh >> 1)) * 4 + qd) * 128 +
                                     (nh & 1) * 4 + j);
        float4 bv4 = *(const float4*)&bv[cv];
#pragma unroll
        for (int r = 0; r < 4; ++r)
          VG[base + (size_t)(quad * 4 + r) * 8] =
              (_Float16)(acc[mi][ni][r] + ((const float*)&bv4)[r]);
      }
    }
  }
}

// ===================== 2-phase/K-tile 128x256 O-projection ==================
// Same template as gemm_qkv8: 256 blocks (32 bm x 8 bn), 512 thr (8 waves
// 2Mx4N, wave 64x64), BK=64 double-buffered, 2 phases x 16 MFMA, counted
// vmcnt(6)/(3) ladder, same XOR swizzle. LDS 96 KiB. C fp32 = A*B^T + bias.
__global__ __launch_bounds__(512, 2)
void gemm_o8(const bf16* __restrict__ A, const bf16* __restrict__ Bm,
             const float* __restrict__ bias, float* __restrict__ C) {
  constexpr int NT = D_ / 64;   // 32 K-tiles
  constexpr int BUFE = 24576;   // elems per buffer: A 2x4096 + B 2x8192
  __shared__ bf16 L[2 * BUFE];  // 96 KiB

  const int id = blockIdx.x;
  const int bn = id & 7;        // XCD-pinned weight slab
  const int bm = id >> 3;

  const int tid = threadIdx.x;
  const int wid = tid >> 6, lane = tid & 63;
  const int lm = lane & 15, quad = lane >> 4;
  const int wm = wid >> 2, wn = wid & 3;   // 2M x 4N

  const int cOff = (quad * 8) ^ (((lm >> 3) & 1) << 4);
  // slots (elems): A-k0 @0, B-k0 @4096, A-k1 @12288, B-k1 @16384
  const bf16* LA0 = L + (wm * 64 + lm) * 32 + cOff;          // +BUF +h*12288 +mi*512
  const bf16* LB0 = L + 4096 + (wn * 64 + lm) * 32 + cOff;   // +BUF +h*12288 +ni*512

  const int r0 = tid >> 2;
  const int csrc = ((tid & 3) * 8) ^ (((tid >> 5) & 1) << 4);
  const bf16* Asrc = A  + (size_t)(bm * 128 + r0) * D_ + csrc;
  const bf16* Bs0  = Bm + (size_t)(bn * 256 + r0) * D_ + csrc;
  const bf16* Bs1  = Bs0 + (size_t)128 * D_;
  bf16* Ld = L + tid * 8;

  floatx4 acc[4][4] = {};

#define STG_A(tt, hh, DB)  async16(Asrc + (tt) * 64 + (hh) * 32, (DB) + (hh) * 12288)
#define STG_B0(tt, hh, DB) async16(Bs0  + (tt) * 64 + (hh) * 32, (DB) + 4096 + (hh) * 12288)
#define STG_B1(tt, hh, DB) async16(Bs1  + (tt) * 64 + (hh) * 32, (DB) + 8192 + (hh) * 12288)

  // prologue: t0 k0+k1 (6) + t1 k0 (3) = 9; wait until t0 k0 (3) landed.
  STG_A(0, 0, Ld); STG_B0(0, 0, Ld); STG_B1(0, 0, Ld);
  STG_A(0, 1, Ld); STG_B0(0, 1, Ld); STG_B1(0, 1, Ld);
  STG_A(1, 0, Ld + BUFE); STG_B0(1, 0, Ld + BUFE); STG_B1(1, 0, Ld + BUFE);
  asm volatile("s_waitcnt vmcnt(6)" ::: "memory");
  BARX();

  auto tile = [&](int t, const int BUF) __attribute__((always_inline)) {
    const bf16* LA = LA0 + BUF;
    const bf16* LB = LB0 + BUF;
    bf16* SD  = Ld + BUF;
    bf16* SDo = Ld + (BUF ^ BUFE);
    const bool s1 = (t + 1) < NT, s2 = (t + 2) < NT;
    bf16x8 aF[4], bF[4];

    // ---- phase A: k-half 0
#pragma unroll
    for (int i = 0; i < 4; ++i) aF[i] = *(const bf16x8*)(LA + i * 512);
#pragma unroll
    for (int i = 0; i < 4; ++i) bF[i] = *(const bf16x8*)(LB + i * 512);
    if (s1) { STG_A(t + 1, 1, SDo); STG_B0(t + 1, 1, SDo); STG_B1(t + 1, 1, SDo); }
    BARX(); LGKM0();
    __builtin_amdgcn_s_setprio(1);
#pragma unroll
    for (int mi = 0; mi < 4; ++mi)
#pragma unroll
      for (int ni = 0; ni < 4; ++ni)
        acc[mi][ni] = MFMA32B(bF[ni], aF[mi], acc[mi][ni]);
    __builtin_amdgcn_s_setprio(0);
    if (s1) { asm volatile("s_waitcnt vmcnt(6)" ::: "memory"); }
    else    { asm volatile("s_waitcnt vmcnt(0)" ::: "memory"); }
    BARX();

    // ---- phase B: k-half 1
#pragma unroll
    for (int i = 0; i < 4; ++i) aF[i] = *(const bf16x8*)(LA + 12288 + i * 512);
#pragma unroll
    for (int i = 0; i < 4; ++i) bF[i] = *(const bf16x8*)(LB + 12288 + i * 512);
    if (s2) { STG_A(t + 2, 0, SD); STG_B0(t + 2, 0, SD); STG_B1(t + 2, 0, SD); }
    BARX(); LGKM0();
    __builtin_amdgcn_s_setprio(1);
#pragma unroll
    for (int mi = 0; mi < 4; ++mi)
#pragma unroll
      for (int ni = 0; ni < 4; ++ni)
        acc[mi][ni] = MFMA32B(bF[ni], aF[mi], acc[mi][ni]);
    __builtin_amdgcn_s_setprio(0);
    if (s2)      { asm volatile("s_waitcnt vmcnt(6)" ::: "memory"); }
    else if (s1) { asm volatile("s_waitcnt vmcnt(3)" ::: "memory"); }
    else         { asm volatile("s_waitcnt vmcnt(0)" ::: "memory"); }
    BARX();
  };

  for (int t = 0; t < NT; t += 2) { tile(t, 0); tile(t + 1, BUFE); }

#undef STG_A
#undef STG_B0
#undef STG_B1

  // swapped layout: lane holds row = ..+lm, cols col0..col0+3
#pragma unroll
  for (int mi = 0; mi < 4; ++mi) {
    const int row = bm * 128 + wm * 64 + mi * 16 + lm;
#pragma unroll
    for (int ni = 0; ni < 4; ++ni) {
      const int col0 = bn * 256 + wn * 64 + ni * 16 + quad * 4;
      float4 bv4 = *(const float4*)&bias[col0];
      float4 o4;
      o4.x = acc[mi][ni][0] + bv4.x; o4.y = acc[mi][ni][1] + bv4.y;
      o4.z = acc[mi][ni][2] + bv4.z; o4.w = acc[mi][ni][3] + bv4.w;
      *(float4*)&C[(size_t)row * D_ + col0] = o4;
    }
  }
}

// -------------------- causal GQA flash attention, v6 ------------------------
// Block = (pair, b, kvh): 4 waves = 4 heads of one GQA group sharing K/V LDS.
// Each wave owns two 16-row q-tiles (hi=127-pair, lo=pair), interleaved kv-loop.
// v6: single merged kc-loop (QK -> mask-in-f32 -> pkrtz -> PV) for ILP;
// V reads as 2x ds_read_b128 per kc (nh-paired layout); setprio around MFMA
// clusters; launch_bounds(256,5) -> 5 blocks/CU (LDS 32KiB x 5 = 160KiB).
__global__ __launch_bounds__(256, 5)
void attn_kernel(const bf16* __restrict__ Q, const bf16* __restrict__ K,
                 const _Float16* __restrict__ VG, bf16* __restrict__ O) {
  const int tid = threadIdx.x;
  const int wid = tid >> 6, lane = tid & 63;
  const int lm = lane & 15, quad = lane >> 4;

  // XCD-aware swizzle: group (b,kvh) pinned to one XCD (2 groups/XCD)
  const int n   = blockIdx.y * 64 + blockIdx.x;   // grid (64, 16)
  const int x3  = n & 7, b1 = (n >> 3) & 1;
  const int pair = n >> 4;                        // 0..63
  const int grp  = x3 * 2 + b1;                   // 0..15 == b*8 + kvh
  const int b    = grp >> 3, kvh = grp & 7;
  const int head = kvh * 4 + wid;

  const int hi = 127 - pair, lo = pair;
  const int nt_hi = (hi >> 2) + 1;                // 17..32
  const int nt_lo = (lo >> 2) + 1;

  __shared__ bf16     Ks[2 * 64 * 64];   // [buf][hd-half][kv][32]
  __shared__ _Float16 Vs[2 * 64 * 64];   // [buf][tiled 4096, nh-paired]

  const int tb[2] = {hi * 16, lo * 16};

  bf16x8 qf[2][2];
#pragma unroll
  for (int tt = 0; tt < 2; ++tt) {
    const size_t qg = ((size_t)(b * S_ + tb[tt] + lm)) * (H_ * HD_) + head * HD_;
#pragma unroll
    for (int kf = 0; kf < 2; ++kf)
      qf[tt][kf] = *(const bf16x8*)&Q[qg + kf * 32 + quad * 8];
  }

  half4 onesh;
#pragma unroll
  for (int j = 0; j < 4; ++j) onesh[j] = (_Float16)1.0f;

  floatx4 o_acc[2][4] = {};
  floatx4 lacc[2] = {};

  auto stage = [&](int t, int buf) {
    const int tr = tid >> 2;
    const int tc = (tid & 3) * 8;
#pragma unroll
    for (int c = 0; c < 2; ++c) {
      async16(&K[(size_t)(b * S_ + t * 64 + tr) * (HKV_ * HD_) + kvh * HD_ + c * 32 + tc],
              &Ks[buf * 4096 + c * 2048 + tid * 8]);
      async16(&VG[((size_t)(grp * 32 + t) << 12) + c * 2048 + tid * 8],
              &Vs[buf * 4096 + c * 2048 + tid * 8]);
    }
  };

  stage(0, 0);

  for (int t = 0; t < nt_hi; ++t) {
    const int cur = t & 1;
    asm volatile("s_waitcnt vmcnt(0)" ::: "memory");
    __syncthreads();
    if (t + 1 < nt_hi) stage(t + 1, cur ^ 1);

    const bf16*     Kb = &Ks[cur * 4096];
    const _Float16* Vb = &Vs[cur * 4096];
    const int t0 = t * 64;
    const int nact = (t < nt_lo) ? 2 : 1;

    int kcmax[2], kcross[2];
#pragma unroll
    for (int tt = 0; tt < 2; ++tt) {
      const int rel = tb[tt] + 15 - t0;
      kcmax[tt]  = (tt < nact) ? ((rel >> 4) >= 3 ? 4 : (rel >> 4) + 1) : 0;
      kcross[tt] = rel >> 4;
    }

    half4 ps[2] = {};   // per-tile row-sum presum (f16)

    // -------- merged kc loop: QK -> softmax -> PV, pipelineable ------------
#pragma unroll
    for (int kc = 0; kc < 4; ++kc) {
      if (kc >= kcmax[0]) break;   // kcmax[0] >= kcmax[1] always
      bf16x8 kb0 = *(const bf16x8*)&Kb[(kc * 16 + lm) * 32 + quad * 8];
      bf16x8 kb1 = *(const bf16x8*)&Kb[2048 + (kc * 16 + lm) * 32 + quad * 8];

      floatx4 sT[2];
      __builtin_amdgcn_s_setprio(1);
#pragma unroll
      for (int tt = 0; tt < 2; ++tt) {
        if (kc >= kcmax[tt]) continue;
        floatx4 s0 = {};
        s0 = MFMA32B(kb0, qf[tt][0], s0);
        sT[tt] = MFMA32B(kb1, qf[tt][1], s0);
      }
      __builtin_amdgcn_s_setprio(0);

      // V fragments for this kc: 2 x b128 (nh pairs 0/1 and 2/3)
      half8 v0 = *(const half8*)&Vb[(kc * 8 + quad) * 128 + lm * 8];
      half8 v1 = *(const half8*)&Vb[(kc * 8 + 4 + quad) * 128 + lm * 8];
      half4 v0l = __builtin_shufflevector(v0, v0, 0, 1, 2, 3);
      half4 v0h = __builtin_shufflevector(v0, v0, 4, 5, 6, 7);
      half4 v1l = __builtin_shufflevector(v1, v1, 0, 1, 2, 3);
      half4 v1h = __builtin_shufflevector(v1, v1, 4, 5, 6, 7);

      half4 pbk[2];
#pragma unroll
      for (int tt = 0; tt < 2; ++tt) {
        if (kc >= kcmax[tt]) continue;
        floatx4 s = sT[tt];
        if (kc == kcross[tt]) {
          const int qrel = tb[tt] + lm - t0;   // q - t0
#pragma unroll
          for (int r = 0; r < 4; ++r)
            if (kc * 16 + quad * 4 + r > qrel) s[r] = -__builtin_inff();
        }
        half2v c0 = pkrtz(EXP2(s[0]), EXP2(s[1]));
        half2v c1 = pkrtz(EXP2(s[2]), EXP2(s[3]));
        half4 pk = __builtin_shufflevector(c0, c1, 0, 1, 2, 3);
        pbk[tt] = pk;
        ps[tt] += pk;
      }

      __builtin_amdgcn_s_setprio(1);
#pragma unroll
      for (int tt = 0; tt < 2; ++tt) {
        if (kc >= kcmax[tt]) continue;
        o_acc[tt][0] = MFMA16H(v0l, pbk[tt], o_acc[tt][0]);
        o_acc[tt][1] = MFMA16H(v0h, pbk[tt], o_acc[tt][1]);
        o_acc[tt][2] = MFMA16H(v1l, pbk[tt], o_acc[tt][2]);
        o_acc[tt][3] = MFMA16H(v1h, pbk[tt], o_acc[tt][3]);
      }
      __builtin_amdgcn_s_setprio(0);
    }

    // row sums: one ones-MFMA per q-tile
#pragma unroll
    for (int tt = 0; tt < 2; ++tt)
      if (kcmax[tt]) lacc[tt] = MFMA16H(onesh, ps[tt], lacc[tt]);
  }

#pragma unroll
  for (int tt = 0; tt < 2; ++tt) {
    const float rl = 1.f / lacc[tt][0];
    const size_t rowg = (size_t)(b * S_ + tb[tt] + lm);
#pragma unroll
    for (int nh = 0; nh < 4; ++nh) {
      alignas(8) bf16 tmp[4];
#pragma unroll
      for (int r = 0; r < 4; ++r)
        tmp[r] = __float2bfloat16(o_acc[tt][nh][r] * rl);
      *(uint2*)&O[rowg * (H_ * HD_) + head * HD_ + nh * 16 + quad * 4] = *(uint2*)tmp;
    }
  }
}

// ---------------------------------------------------------------------------
extern "C" void kernel_launch(void* const* d_in, const int* in_sizes, int n_in,
                              void* d_out, int out_size, void* d_ws, size_t ws_size,
                              hipStream_t stream) {
  (void)in_sizes; (void)n_in; (void)out_size; (void)ws_size;
  const float* x  = (const float*)d_in[0];
  const float* wq = (const float*)d_in[1];
  const float* bq = (const float*)d_in[2];
  const float* wk = (const float*)d_in[3];
  const float* bk = (const float*)d_in[4];
  const float* wv = (const float*)d_in[5];
  const float* bv = (const float*)d_in[6];
  const float* wo = (const float*)d_in[7];
  const float* bo = (const float*)d_in[8];
  float* out = (float*)d_out;

  const int M = B_ * S_;        // 4096
  const int E = H_ * HD_;       // 2048
  const int EKV = HKV_ * HD_;   // 512

  char* ws = (char*)d_ws;
  size_t off = 0;
  auto alloc = [&](size_t bytes) {
    char* p = ws + off;
    off += (bytes + 255) & ~(size_t)255;
    return p;
  };
  bf16* xb   = (bf16*)alloc((size_t)M * D_ * 2);
  bf16* Wcat = (bf16*)alloc((size_t)(E + 2 * EKV) * D_ * 2);   // [wq|wk|wv] rows
  bf16* wob  = (bf16*)alloc((size_t)D_ * E * 2);
  bf16* Qb   = (bf16*)alloc((size_t)M * E * 2);
  bf16* Kb   = (bf16*)alloc((size_t)M * EKV * 2);
  _Float16* VG = (_Float16*)alloc((size_t)M * EKV * 2);  // tiled V, f16
  bf16* Ob   = (bf16*)alloc((size_t)M * E * 2);

  bf16* wqb = Wcat;                          // rows 0..2047 (pre-scaled)
  bf16* wkb = Wcat + (size_t)E * D_;         // rows 2048..2559
  bf16* wvb = Wcat + (size_t)(E + EKV) * D_; // rows 2560..3071

  f2b_all<<<9216, 256, 0, stream>>>(x, wq, wk, wv, wo, xb, wqb, wkb, wvb, wob);

  gemm_qkv8<<<dim3(256), dim3(512), 0, stream>>>(xb, Wcat, bq, bk, bv,
                                                 Qb, Kb, VG);

  attn_kernel<<<dim3(64, 16), 256, 0, stream>>>(Qb, Kb, VG, Ob);

  gemm_o8<<<dim3(256), dim3(512), 0, stream>>>(Ob, wob, bo, out);
}